// Round 6
// baseline (300.600 us; speedup 1.0000x reference)
//
#include <hip/hip_runtime.h>
#include <hip/hip_bf16.h>

#define HW 3600
#define NQ 28800
#define CIN 256
#define CMID 128
#define NSHARD 16

typedef short bf16x8 __attribute__((ext_vector_type(8)));
typedef float f32x4 __attribute__((ext_vector_type(4)));

#define INV_T 14.285714285714286f
#define SQRT_SCALE 4.539816f          /* sqrt(INV_T * log2(e)) */
#define LN2F 0.6931471805599453f

__device__ inline unsigned short f2bf(float f) {
  unsigned u = __float_as_uint(f);
  return (unsigned short)((u + 0x7fffu + ((u >> 16) & 1u)) >> 16);  // RNE
}
__device__ inline float bf2f(unsigned short h) { return __uint_as_float((unsigned)h << 16); }

// ---------------- prep: fp32 weights -> bf16 (native row-major [out][in] = A-frag layout)
__global__ void prep_kernel(const float* __restrict__ conv_w, const float* __restrict__ lin_w,
                            unsigned short* __restrict__ cw16, unsigned short* __restrict__ lw16) {
  const int i = blockIdx.x * 256 + threadIdx.x;
  if (i < 128 * 256) cw16[i] = f2bf(conv_w[i]);
  if (i < 128 * 128) lw16[i] = f2bf(lin_w[i]);
}

// ---------------- conv1 (MFMA), both branches in one launch (blockIdx.z):
// yt[z][q][co] = sum_ci W[co][ci]*relu(x_z[ci][q])  (raw, no bias), + sharded per-co stats.
// xT: row stride 40 elems + 16B-block XOR swizzle -> writes ~2-way, b128 reads ~free.
__global__ __launch_bounds__(256, 4) void conv1_mfma_kernel(
    const float* __restrict__ x0, const float* __restrict__ x1,
    const unsigned short* __restrict__ cw16,
    unsigned short* __restrict__ yt, float* __restrict__ stats) {
  __shared__ __align__(16) unsigned short xT[64 * 40];   // [q_local][ci_local swizzled]
  __shared__ float sredw[4][128];
  __shared__ float s2redw[4][128];
  const int z = blockIdx.z;
  const float* x = z ? x1 : x0;
  float* st = stats + (z * NSHARD + (blockIdx.x & (NSHARD - 1))) * 256;
  unsigned short* yz = yt + (size_t)z * NQ * 128;

  const int t = threadIdx.x;
  const int w = t >> 6;
  const int l = t & 63;
  const int lr = l & 15;
  const int lg = l >> 4;
  const int q0 = blockIdx.x * 64;

  f32x4 acc[8];
#pragma unroll
  for (int tile = 0; tile < 8; tile++) acc[tile] = (f32x4){0.f, 0.f, 0.f, 0.f};

  // staging column base: q is 4-aligned and HW%4==0, so a float4 never crosses a batch
  const int kq = t & 15;                 // row group: rows 4*kq..4*kq+3
  const int qcol = q0 + 4 * kq;
  const int bb = qcol / HW;
  const int pp = qcol - bb * HW;
  const float* xcol = x + (size_t)bb * CIN * HW + pp;
  const int cil0 = (t >> 4);             // 0..15
  const int cil1 = cil0 + 16;            // 16..31
  // swizzled columns (XOR 16B block with row>>2 = kq)
  const int c0s = (cil0 & 7) | ((((cil0 >> 3) ^ kq) & 3) << 3);
  const int c1s = (cil1 & 7) | ((((cil1 >> 3) ^ kq) & 3) << 3);

  float4 v0 = *(const float4*)&xcol[(size_t)cil0 * HW];
  float4 v1 = *(const float4*)&xcol[(size_t)cil1 * HW];

  const int rdoff = (w * 16 + lr) * 40 + (((lg ^ ((w * 16 + lr) >> 2)) & 3) << 3);

  for (int ch = 0; ch < 8; ch++) {
    if (ch) __syncthreads();   // previous chunk's LDS reads done
    {
      unsigned short* dst = &xT[(4 * kq) * 40 + c0s];
      dst[0]   = f2bf(fmaxf(v0.x, 0.f));
      dst[40]  = f2bf(fmaxf(v0.y, 0.f));
      dst[80]  = f2bf(fmaxf(v0.z, 0.f));
      dst[120] = f2bf(fmaxf(v0.w, 0.f));
      dst = &xT[(4 * kq) * 40 + c1s];
      dst[0]   = f2bf(fmaxf(v1.x, 0.f));
      dst[40]  = f2bf(fmaxf(v1.y, 0.f));
      dst[80]  = f2bf(fmaxf(v1.z, 0.f));
      dst[120] = f2bf(fmaxf(v1.w, 0.f));
    }
    __syncthreads();           // writes visible
    if (ch < 7) {              // prefetch next chunk (overlaps MFMAs below)
      v0 = *(const float4*)&xcol[(size_t)((ch + 1) * 32 + cil0) * HW];
      v1 = *(const float4*)&xcol[(size_t)((ch + 1) * 32 + cil1) * HW];
    }
    bf16x8 bv = *(const bf16x8*)&xT[rdoff];
#pragma unroll
    for (int tile = 0; tile < 8; tile++) {
      bf16x8 av = *(const bf16x8*)&cw16[(size_t)(tile * 16 + lr) * 256 + ch * 32 + lg * 8];
      acc[tile] = __builtin_amdgcn_mfma_f32_16x16x32_bf16(av, bv, acc[tile], 0, 0, 0);
    }
  }

  // stats: reduce each (co) over the 16 cols held by the lr-group
#pragma unroll
  for (int tile = 0; tile < 8; tile++) {
#pragma unroll
    for (int i = 0; i < 4; i++) {
      float v = acc[tile][i];
      float v2 = v * v;
      v += __shfl_xor(v, 1); v2 += __shfl_xor(v2, 1);
      v += __shfl_xor(v, 2); v2 += __shfl_xor(v2, 2);
      v += __shfl_xor(v, 4); v2 += __shfl_xor(v2, 4);
      v += __shfl_xor(v, 8); v2 += __shfl_xor(v2, 8);
      if (lr == 0) {
        sredw[w][tile * 16 + lg * 4 + i] = v;
        s2redw[w][tile * 16 + lg * 4 + i] = v2;
      }
    }
  }

  // store yt (bf16, transposed [q][co] = conv2's B-frag layout)
  const int q = q0 + w * 16 + lr;
#pragma unroll
  for (int tile = 0; tile < 8; tile++) {
    union { unsigned short u[4]; uint2 v; } pk;
#pragma unroll
    for (int i = 0; i < 4; i++) pk.u[i] = f2bf(acc[tile][i]);
    *(uint2*)&yz[(size_t)q * 128 + tile * 16 + lg * 4] = pk.v;
  }

  __syncthreads();
  if (t < 128) {
    atomicAdd(&st[t], sredw[0][t] + sredw[1][t] + sredw[2][t] + sredw[3][t]);
    atomicAdd(&st[128 + t], s2redw[0][t] + s2redw[1][t] + s2redw[2][t] + s2redw[3][t]);
  }
}

// ---------------- BN fold, both branches (blockIdx.x = z), summing shards:
// y = acc + cb; mean = E[acc]+cb; var = E[acc^2]-E[acc]^2;  BN(y) = acc*s + (cb*s + t)
__global__ void scale_kernel(const float* __restrict__ stats, const float* __restrict__ conv_b,
                             const float* __restrict__ gamma, const float* __restrict__ beta,
                             float* __restrict__ sc) {
  const int z = blockIdx.x;
  const float* st = stats + z * NSHARD * 256;
  float* scz = sc + z * 256;
  const int c = threadIdx.x;
  float s1 = 0.f, s2 = 0.f;
#pragma unroll
  for (int sh = 0; sh < NSHARD; sh++) {
    s1 += st[sh * 256 + c];
    s2 += st[sh * 256 + 128 + c];
  }
  const float inv_n = 1.f / (float)NQ;
  const float macc = s1 * inv_n;
  const float var = s2 * inv_n - macc * macc;
  const float mean = macc + conv_b[c];
  const float s = gamma[c] * rsqrtf(var + 1e-5f);
  const float tt = beta[c] - mean * s;
  scz[c] = s;
  scz[128 + c] = conv_b[c] * s + tt;
}

// ---------------- conv2 (MFMA) + L2-normalize (sqrt(INV_T*log2e) folded), both branches
__global__ __launch_bounds__(256, 4) void conv2_mfma_kernel(
    const unsigned short* __restrict__ yt, const unsigned short* __restrict__ lw16,
    const float* __restrict__ sc, const float* __restrict__ lin_b,
    unsigned short* __restrict__ feat_o, unsigned short* __restrict__ feat_t) {
  const int z = blockIdx.z;
  const unsigned short* yz = yt + (size_t)z * NQ * 128;
  const float* scz = sc + z * 256;
  unsigned short* feat = z ? feat_t : feat_o;

  const int t = threadIdx.x;
  const int w = t >> 6;
  const int l = t & 63;
  const int lr = l & 15;
  const int lg = l >> 4;
  const int q = blockIdx.x * 64 + w * 16 + lr;

  f32x4 acc[8];
#pragma unroll
  for (int tile = 0; tile < 8; tile++) acc[tile] = (f32x4){0.f, 0.f, 0.f, 0.f};

  const unsigned short* yrow = yz + (size_t)q * 128;
  for (int ch = 0; ch < 4; ch++) {
    bf16x8 raw = *(const bf16x8*)&yrow[ch * 32 + lg * 8];
    bf16x8 bv;
#pragma unroll
    for (int e = 0; e < 8; e++) {
      const int c = ch * 32 + lg * 8 + e;
      float v = fmaxf(fmaf(bf2f((unsigned short)raw[e]), scz[c], scz[128 + c]), 0.f);
      bv[e] = (short)f2bf(v);
    }
#pragma unroll
    for (int tile = 0; tile < 8; tile++) {
      bf16x8 av = *(const bf16x8*)&lw16[(size_t)(tile * 16 + lr) * 128 + ch * 32 + lg * 8];
      acc[tile] = __builtin_amdgcn_mfma_f32_16x16x32_bf16(av, bv, acc[tile], 0, 0, 0);
    }
  }

  float vals[8][4];
  float ssq = 0.f;
#pragma unroll
  for (int tile = 0; tile < 8; tile++) {
#pragma unroll
    for (int i = 0; i < 4; i++) {
      float v = acc[tile][i] + lin_b[tile * 16 + lg * 4 + i];
      vals[tile][i] = v;
      ssq += v * v;
    }
  }
  ssq += __shfl_xor(ssq, 16);   // across the 4 lane-groups holding the same column q
  ssq += __shfl_xor(ssq, 32);
  const float inv = SQRT_SCALE / fmaxf(sqrtf(ssq), 1e-12f);

#pragma unroll
  for (int tile = 0; tile < 8; tile++) {
    union { unsigned short u[4]; uint2 v; } pk;
#pragma unroll
    for (int i = 0; i < 4; i++) pk.u[i] = f2bf(vals[tile][i] * inv);
    *(uint2*)&feat[(size_t)q * 128 + tile * 16 + lg * 4] = pk.v;
  }
}

// ---------------- InfoNCE v5: grid 1800 = 8 batches (XCD-pinned) x 15 rowblks x 15 colgs.
// Block: 4 waves x 64 rows, double-buffered LDS B-chunks (48 cols each, 5 chunks).
// Features carry sqrt(INV_T*log2e): acc IS the exp2 argument (bounded by 20.6 -> no shift).
// Partial col-sums go to slab[colg][b][r] via plain stores (rows block-exclusive).
__global__ __launch_bounds__(256, 4) void infonce_kernel(
    const unsigned short* __restrict__ fo, const unsigned short* __restrict__ ft,
    float* __restrict__ slab) {
  __shared__ __align__(16) unsigned short Bs[2][6144];   // 2 x 12,288 B
  const int id = blockIdx.x;
  const int b = id & 7;                 // XCD-aligned batch
  const int within = id >> 3;           // 0..224
  const int rowblk = within % 15;
  const int colg = within / 15;         // 0..14
  const int t = threadIdx.x;
  const int w = t >> 6;
  const int lane = t & 63;
  const int lr = lane & 15;
  const int lkq = lane >> 4;            // 0..3
  const int base = rowblk * 256 + w * 64;
  const unsigned short* fob = fo + (size_t)b * HW * 128;
  const unsigned short* ftb = ft + (size_t)b * HW * 128;

  // A fragments: 64 rows resident (clamped; stores masked later)
  bf16x8 a[4][4];                       // [tile][kk]
#pragma unroll
  for (int tile = 0; tile < 4; tile++) {
    const int r = min(base + tile * 16 + lr, HW - 1);
    const unsigned short* ap = fob + (size_t)r * 128 + lkq * 8;
#pragma unroll
    for (int kk = 0; kk < 4; kk++) a[tile][kk] = *(const bf16x8*)(ap + kk * 32);
  }
  float rs[4][4];
#pragma unroll
  for (int tile = 0; tile < 4; tile++)
#pragma unroll
    for (int i = 0; i < 4; i++) rs[tile][i] = 0.f;

  // staging gather offsets: this thread stages frags f = {w, w+4, w+8};
  // frag f=(kk*3+sub), slot lane holds ft[cbase+sub*16+(lane&15)][kk*32+(lane>>4)*8 ..+7]
  int rowoff[3];
#pragma unroll
  for (int i = 0; i < 3; i++) {
    const int f = i * 4 + w;
    const int kk = f / 3;
    const int sub = f - kk * 3;
    rowoff[i] = (sub * 16 + lr) * 128 + kk * 32 + lkq * 8;
  }

  uint4 r[3];
  {
    const unsigned short* p = ftb + (size_t)(colg * 5) * 48 * 128;
#pragma unroll
    for (int i = 0; i < 3; i++) r[i] = *(const uint4*)(p + rowoff[i]);
  }

  for (int it = 0; it < 5; it++) {
    unsigned short* bufp = &Bs[it & 1][0];
#pragma unroll
    for (int i = 0; i < 3; i++)
      *(uint4*)&bufp[(i * 4 + w) * 512 + lane * 8] = r[i];   // waits vmcnt on r
    __syncthreads();
    if (it < 4) {                       // prefetch next chunk, hides under compute
      const unsigned short* p = ftb + (size_t)(colg * 5 + it + 1) * 48 * 128;
#pragma unroll
      for (int i = 0; i < 3; i++) r[i] = *(const uint4*)(p + rowoff[i]);
    }
    f32x4 acc[4][3];
#pragma unroll
    for (int tile = 0; tile < 4; tile++)
#pragma unroll
      for (int sub = 0; sub < 3; sub++) acc[tile][sub] = (f32x4){0.f, 0.f, 0.f, 0.f};
#pragma unroll
    for (int kk = 0; kk < 4; kk++) {
      bf16x8 bv[3];
#pragma unroll
      for (int sub = 0; sub < 3; sub++)
        bv[sub] = *(const bf16x8*)&bufp[(kk * 3 + sub) * 512 + lane * 8];
#pragma unroll
      for (int tile = 0; tile < 4; tile++)
#pragma unroll
        for (int sub = 0; sub < 3; sub++)
          acc[tile][sub] = __builtin_amdgcn_mfma_f32_16x16x32_bf16(
              a[tile][kk], bv[sub], acc[tile][sub], 0, 0, 0);
    }
#pragma unroll
    for (int tile = 0; tile < 4; tile++)
#pragma unroll
      for (int sub = 0; sub < 3; sub++)
#pragma unroll
        for (int i = 0; i < 4; i++)
          rs[tile][i] += exp2f(acc[tile][sub][i]);
    // single barrier per iter is sufficient with the double buffer (verified r4/r5)
  }

  // reduce col-partials over lanes 0-15 of each group
#pragma unroll
  for (int tile = 0; tile < 4; tile++)
#pragma unroll
    for (int i = 0; i < 4; i++) {
      float v = rs[tile][i];
      v += __shfl_xor(v, 1); v += __shfl_xor(v, 2);
      v += __shfl_xor(v, 4); v += __shfl_xor(v, 8);
      rs[tile][i] = v;
    }
  if (lr == 0) {
    float* out = slab + (size_t)colg * NQ + b * HW;
#pragma unroll
    for (int tile = 0; tile < 4; tile++)
#pragma unroll
      for (int i = 0; i < 4; i++) {
        const int rr = base + tile * 16 + lkq * 4 + i;
        if (rr < HW) out[rr] = rs[tile][i];
      }
  }
}

// ---------------- final: mean over q of (log(sum_colg slab) - dot*ln2)
// (features carry sqrt(INV_T*log2e), so dot*ln2 == raw_dot*INV_T)
__global__ __launch_bounds__(256) void final_kernel(
    const float* __restrict__ slab, const unsigned short* __restrict__ fo,
    const unsigned short* __restrict__ ft, float* __restrict__ out) {
  const int q = blockIdx.x * 256 + threadIdx.x;
  float val = 0.f;
  if (q < NQ) {
    float se = 0.f;
#pragma unroll
    for (int s = 0; s < 15; s++) se += slab[(size_t)s * NQ + q];
    const unsigned short* a = fo + (size_t)q * 128;
    const unsigned short* c = ft + (size_t)q * 128;
    float dot = 0.f;
#pragma unroll
    for (int k = 0; k < 128; k += 8) {
      bf16x8 ua = *(const bf16x8*)(a + k);
      bf16x8 ub = *(const bf16x8*)(c + k);
#pragma unroll
      for (int e = 0; e < 8; e++)
        dot = fmaf(bf2f((unsigned short)ua[e]), bf2f((unsigned short)ub[e]), dot);
    }
    val = logf(se) - dot * LN2F;
  }
#pragma unroll
  for (int m = 1; m < 64; m <<= 1) val += __shfl_xor(val, m);
  __shared__ float red[4];
  const int wid = threadIdx.x >> 6;
  if ((threadIdx.x & 63) == 0) red[wid] = val;
  __syncthreads();
  if (threadIdx.x == 0)
    atomicAdd(out, (red[0] + red[1] + red[2] + red[3]) * (1.f / (float)NQ));
}

extern "C" void kernel_launch(void* const* d_in, const int* in_sizes, int n_in,
                              void* d_out, int out_size, void* d_ws, size_t ws_size,
                              hipStream_t stream) {
  (void)in_sizes; (void)n_in; (void)out_size; (void)ws_size;
  const float* x_orig = (const float*)d_in[0];
  const float* x_trans = (const float*)d_in[1];
  const float* conv_w = (const float*)d_in[2];
  const float* conv_b = (const float*)d_in[3];
  const float* gamma = (const float*)d_in[4];
  const float* beta = (const float*)d_in[5];
  const float* lin_w = (const float*)d_in[6];
  const float* lin_b = (const float*)d_in[7];
  float* out = (float*)d_out;

  char* ws = (char*)d_ws;
  unsigned short* yt = (unsigned short*)(ws + 0);            // 2 x 7,372,800 B (phase A)
  float* slab = (float*)(ws + 0);                            // 15 x 28800 x 4 = 1,728,000 B
                                                             //   (aliases yt: dead by infonce)
  unsigned short* cw16 = (unsigned short*)(ws + 14745600);   //     65,536 B
  unsigned short* lw16 = (unsigned short*)(ws + 14811136);   //     32,768 B
  float* stats = (float*)(ws + 14843904);                    //     32,768 B (2 x 16 x 256)
  float* sc = (float*)(ws + 14876672);                       //      2,048 B
  unsigned short* feat_o = (unsigned short*)(ws + 14878720); //  7,372,800 B
  unsigned short* feat_t = (unsigned short*)(ws + 22251520); //  7,372,800 B
  // end: 29,624,320 B

  hipMemsetAsync(stats, 0, 32768, stream);
  hipMemsetAsync(d_out, 0, sizeof(float), stream);

  prep_kernel<<<128, 256, 0, stream>>>(conv_w, lin_w, cw16, lw16);

  conv1_mfma_kernel<<<dim3(450, 1, 2), 256, 0, stream>>>(x_orig, x_trans, cw16, yt, stats);
  scale_kernel<<<2, 128, 0, stream>>>(stats, conv_b, gamma, beta, sc);
  conv2_mfma_kernel<<<dim3(450, 1, 2), 256, 0, stream>>>(yt, lw16, sc, lin_b, feat_o, feat_t);

  infonce_kernel<<<1800, 256, 0, stream>>>(feat_o, feat_t, slab);
  final_kernel<<<113, 256, 0, stream>>>(slab, feat_o, feat_t, out);
}

// Round 8
// 242.156 us; speedup vs baseline: 1.2413x; 1.2413x over previous
//
#include <hip/hip_runtime.h>
#include <hip/hip_bf16.h>

#define HW 3600
#define NQ 28800
#define CIN 256
#define CMID 128
#define NSHARD 16

typedef short bf16x8 __attribute__((ext_vector_type(8)));
typedef float f32x4 __attribute__((ext_vector_type(4)));

#define INV_T 14.285714285714286f
#define SQRT_SCALE 4.539816f          /* sqrt(INV_T * log2(e)) */
#define LN2F 0.6931471805599453f

__device__ inline unsigned short f2bf(float f) {
  unsigned u = __float_as_uint(f);
  return (unsigned short)((u + 0x7fffu + ((u >> 16) & 1u)) >> 16);  // RNE
}
__device__ inline float bf2f(unsigned short h) { return __uint_as_float((unsigned)h << 16); }

// ---------------- prep: fp32 weights -> bf16 (native row-major [out][in] = A-frag layout)
__global__ void prep_kernel(const float* __restrict__ conv_w, const float* __restrict__ lin_w,
                            unsigned short* __restrict__ cw16, unsigned short* __restrict__ lw16) {
  const int i = blockIdx.x * 256 + threadIdx.x;
  if (i < 128 * 256) cw16[i] = f2bf(conv_w[i]);
  if (i < 128 * 128) lw16[i] = f2bf(lin_w[i]);
}

// ---------------- conv1 (MFMA), both branches in one launch (blockIdx.z):
// yt[z][q][co] = sum_ci W[co][ci]*relu(x_z[ci][q])  (raw, no bias), + sharded per-co stats.
// xT: row stride 40 elems + 16B-block XOR swizzle -> writes ~2-way, b128 reads ~free.
__global__ __launch_bounds__(256, 4) void conv1_mfma_kernel(
    const float* __restrict__ x0, const float* __restrict__ x1,
    const unsigned short* __restrict__ cw16,
    unsigned short* __restrict__ yt, float* __restrict__ stats) {
  __shared__ __align__(16) unsigned short xT[64 * 40];   // [q_local][ci_local swizzled]
  __shared__ float sredw[4][128];
  __shared__ float s2redw[4][128];
  const int z = blockIdx.z;
  const float* x = z ? x1 : x0;
  float* st = stats + (z * NSHARD + (blockIdx.x & (NSHARD - 1))) * 256;
  unsigned short* yz = yt + (size_t)z * NQ * 128;

  const int t = threadIdx.x;
  const int w = t >> 6;
  const int l = t & 63;
  const int lr = l & 15;
  const int lg = l >> 4;
  const int q0 = blockIdx.x * 64;

  f32x4 acc[8];
#pragma unroll
  for (int tile = 0; tile < 8; tile++) acc[tile] = (f32x4){0.f, 0.f, 0.f, 0.f};

  // staging column base: q is 4-aligned and HW%4==0, so a float4 never crosses a batch
  const int kq = t & 15;                 // row group: rows 4*kq..4*kq+3
  const int qcol = q0 + 4 * kq;
  const int bb = qcol / HW;
  const int pp = qcol - bb * HW;
  const float* xcol = x + (size_t)bb * CIN * HW + pp;
  const int cil0 = (t >> 4);             // 0..15
  const int cil1 = cil0 + 16;            // 16..31
  // swizzled columns (XOR 16B block with row>>2 = kq)
  const int c0s = (cil0 & 7) | ((((cil0 >> 3) ^ kq) & 3) << 3);
  const int c1s = (cil1 & 7) | ((((cil1 >> 3) ^ kq) & 3) << 3);

  float4 v0 = *(const float4*)&xcol[(size_t)cil0 * HW];
  float4 v1 = *(const float4*)&xcol[(size_t)cil1 * HW];

  const int rdoff = (w * 16 + lr) * 40 + (((lg ^ ((w * 16 + lr) >> 2)) & 3) << 3);

  for (int ch = 0; ch < 8; ch++) {
    if (ch) __syncthreads();   // previous chunk's LDS reads done
    {
      unsigned short* dst = &xT[(4 * kq) * 40 + c0s];
      dst[0]   = f2bf(fmaxf(v0.x, 0.f));
      dst[40]  = f2bf(fmaxf(v0.y, 0.f));
      dst[80]  = f2bf(fmaxf(v0.z, 0.f));
      dst[120] = f2bf(fmaxf(v0.w, 0.f));
      dst = &xT[(4 * kq) * 40 + c1s];
      dst[0]   = f2bf(fmaxf(v1.x, 0.f));
      dst[40]  = f2bf(fmaxf(v1.y, 0.f));
      dst[80]  = f2bf(fmaxf(v1.z, 0.f));
      dst[120] = f2bf(fmaxf(v1.w, 0.f));
    }
    __syncthreads();           // writes visible
    if (ch < 7) {              // prefetch next chunk (overlaps MFMAs below)
      v0 = *(const float4*)&xcol[(size_t)((ch + 1) * 32 + cil0) * HW];
      v1 = *(const float4*)&xcol[(size_t)((ch + 1) * 32 + cil1) * HW];
    }
    bf16x8 bv = *(const bf16x8*)&xT[rdoff];
#pragma unroll
    for (int tile = 0; tile < 8; tile++) {
      bf16x8 av = *(const bf16x8*)&cw16[(size_t)(tile * 16 + lr) * 256 + ch * 32 + lg * 8];
      acc[tile] = __builtin_amdgcn_mfma_f32_16x16x32_bf16(av, bv, acc[tile], 0, 0, 0);
    }
  }

  // stats: reduce each (co) over the 16 cols held by the lr-group
#pragma unroll
  for (int tile = 0; tile < 8; tile++) {
#pragma unroll
    for (int i = 0; i < 4; i++) {
      float v = acc[tile][i];
      float v2 = v * v;
      v += __shfl_xor(v, 1); v2 += __shfl_xor(v2, 1);
      v += __shfl_xor(v, 2); v2 += __shfl_xor(v2, 2);
      v += __shfl_xor(v, 4); v2 += __shfl_xor(v2, 4);
      v += __shfl_xor(v, 8); v2 += __shfl_xor(v2, 8);
      if (lr == 0) {
        sredw[w][tile * 16 + lg * 4 + i] = v;
        s2redw[w][tile * 16 + lg * 4 + i] = v2;
      }
    }
  }

  // store yt (bf16, transposed [q][co] = conv2's B-frag layout)
  const int q = q0 + w * 16 + lr;
#pragma unroll
  for (int tile = 0; tile < 8; tile++) {
    union { unsigned short u[4]; uint2 v; } pk;
#pragma unroll
    for (int i = 0; i < 4; i++) pk.u[i] = f2bf(acc[tile][i]);
    *(uint2*)&yz[(size_t)q * 128 + tile * 16 + lg * 4] = pk.v;
  }

  __syncthreads();
  if (t < 128) {
    atomicAdd(&st[t], sredw[0][t] + sredw[1][t] + sredw[2][t] + sredw[3][t]);
    atomicAdd(&st[128 + t], s2redw[0][t] + s2redw[1][t] + s2redw[2][t] + s2redw[3][t]);
  }
}

// ---------------- BN fold, both branches (blockIdx.x = z), summing shards:
// y = acc + cb; mean = E[acc]+cb; var = E[acc^2]-E[acc]^2;  BN(y) = acc*s + (cb*s + t)
__global__ void scale_kernel(const float* __restrict__ stats, const float* __restrict__ conv_b,
                             const float* __restrict__ gamma, const float* __restrict__ beta,
                             float* __restrict__ sc) {
  const int z = blockIdx.x;
  const float* st = stats + z * NSHARD * 256;
  float* scz = sc + z * 256;
  const int c = threadIdx.x;
  float s1 = 0.f, s2 = 0.f;
#pragma unroll
  for (int sh = 0; sh < NSHARD; sh++) {
    s1 += st[sh * 256 + c];
    s2 += st[sh * 256 + 128 + c];
  }
  const float inv_n = 1.f / (float)NQ;
  const float macc = s1 * inv_n;
  const float var = s2 * inv_n - macc * macc;
  const float mean = macc + conv_b[c];
  const float s = gamma[c] * rsqrtf(var + 1e-5f);
  const float tt = beta[c] - mean * s;
  scz[c] = s;
  scz[128 + c] = conv_b[c] * s + tt;
}

// ---------------- conv2 (MFMA) + L2-normalize (sqrt(INV_T*log2e) folded), both branches
__global__ __launch_bounds__(256, 4) void conv2_mfma_kernel(
    const unsigned short* __restrict__ yt, const unsigned short* __restrict__ lw16,
    const float* __restrict__ sc, const float* __restrict__ lin_b,
    unsigned short* __restrict__ feat_o, unsigned short* __restrict__ feat_t) {
  const int z = blockIdx.z;
  const unsigned short* yz = yt + (size_t)z * NQ * 128;
  const float* scz = sc + z * 256;
  unsigned short* feat = z ? feat_t : feat_o;

  const int t = threadIdx.x;
  const int w = t >> 6;
  const int l = t & 63;
  const int lr = l & 15;
  const int lg = l >> 4;
  const int q = blockIdx.x * 64 + w * 16 + lr;

  f32x4 acc[8];
#pragma unroll
  for (int tile = 0; tile < 8; tile++) acc[tile] = (f32x4){0.f, 0.f, 0.f, 0.f};

  const unsigned short* yrow = yz + (size_t)q * 128;
  for (int ch = 0; ch < 4; ch++) {
    bf16x8 raw = *(const bf16x8*)&yrow[ch * 32 + lg * 8];
    bf16x8 bv;
#pragma unroll
    for (int e = 0; e < 8; e++) {
      const int c = ch * 32 + lg * 8 + e;
      float v = fmaxf(fmaf(bf2f((unsigned short)raw[e]), scz[c], scz[128 + c]), 0.f);
      bv[e] = (short)f2bf(v);
    }
#pragma unroll
    for (int tile = 0; tile < 8; tile++) {
      bf16x8 av = *(const bf16x8*)&lw16[(size_t)(tile * 16 + lr) * 128 + ch * 32 + lg * 8];
      acc[tile] = __builtin_amdgcn_mfma_f32_16x16x32_bf16(av, bv, acc[tile], 0, 0, 0);
    }
  }

  float vals[8][4];
  float ssq = 0.f;
#pragma unroll
  for (int tile = 0; tile < 8; tile++) {
#pragma unroll
    for (int i = 0; i < 4; i++) {
      float v = acc[tile][i] + lin_b[tile * 16 + lg * 4 + i];
      vals[tile][i] = v;
      ssq += v * v;
    }
  }
  ssq += __shfl_xor(ssq, 16);   // across the 4 lane-groups holding the same column q
  ssq += __shfl_xor(ssq, 32);
  const float inv = SQRT_SCALE / fmaxf(sqrtf(ssq), 1e-12f);

#pragma unroll
  for (int tile = 0; tile < 8; tile++) {
    union { unsigned short u[4]; uint2 v; } pk;
#pragma unroll
    for (int i = 0; i < 4; i++) pk.u[i] = f2bf(vals[tile][i] * inv);
    *(uint2*)&feat[(size_t)q * 128 + tile * 16 + lg * 4] = pk.v;
  }
}

// ---------------- InfoNCE v5b: grid 1800 = 8 batches (XCD-pinned) x 15 rowblks x 15 colgs.
// Block: 4 waves x 64 rows, double-buffered LDS B-chunks (48 cols each, 5 chunks).
// Features carry sqrt(INV_T*log2e): acc IS the exp2 argument (bounded by 20.6 -> no shift).
// Partial col-sums go to slab[colg][b][r] via plain stores (rows block-exclusive).
// launch_bounds (256,2): r6's (256,4) capped VGPR at 64 -> 486 MB/dispatch scratch spill.
__global__ __launch_bounds__(256, 2) void infonce_kernel(
    const unsigned short* __restrict__ fo, const unsigned short* __restrict__ ft,
    float* __restrict__ slab) {
  __shared__ __align__(16) unsigned short Bs[2][6144];   // 2 x 12,288 B
  const int id = blockIdx.x;
  const int b = id & 7;                 // XCD-aligned batch
  const int within = id >> 3;           // 0..224
  const int rowblk = within % 15;
  const int colg = within / 15;         // 0..14
  const int t = threadIdx.x;
  const int w = t >> 6;
  const int lane = t & 63;
  const int lr = lane & 15;
  const int lkq = lane >> 4;            // 0..3
  const int base = rowblk * 256 + w * 64;
  const unsigned short* fob = fo + (size_t)b * HW * 128;
  const unsigned short* ftb = ft + (size_t)b * HW * 128;

  // A fragments: 64 rows resident (clamped; stores masked later)
  bf16x8 a[4][4];                       // [tile][kk]
#pragma unroll
  for (int tile = 0; tile < 4; tile++) {
    const int r = min(base + tile * 16 + lr, HW - 1);
    const unsigned short* ap = fob + (size_t)r * 128 + lkq * 8;
#pragma unroll
    for (int kk = 0; kk < 4; kk++) a[tile][kk] = *(const bf16x8*)(ap + kk * 32);
  }
  float rs[4][4];
#pragma unroll
  for (int tile = 0; tile < 4; tile++)
#pragma unroll
    for (int i = 0; i < 4; i++) rs[tile][i] = 0.f;

  // staging gather offsets: this thread stages frags f = {w, w+4, w+8};
  // frag f=(kk*3+sub), slot lane holds ft[cbase+sub*16+(lane&15)][kk*32+(lane>>4)*8 ..+7]
  int rowoff[3];
#pragma unroll
  for (int i = 0; i < 3; i++) {
    const int f = i * 4 + w;
    const int kk = f / 3;
    const int sub = f - kk * 3;
    rowoff[i] = (sub * 16 + lr) * 128 + kk * 32 + lkq * 8;
  }

  uint4 r[3];
  {
    const unsigned short* p = ftb + (size_t)(colg * 5) * 48 * 128;
#pragma unroll
    for (int i = 0; i < 3; i++) r[i] = *(const uint4*)(p + rowoff[i]);
  }

  for (int it = 0; it < 5; it++) {
    unsigned short* bufp = &Bs[it & 1][0];
#pragma unroll
    for (int i = 0; i < 3; i++)
      *(uint4*)&bufp[(i * 4 + w) * 512 + lane * 8] = r[i];   // waits vmcnt on r
    __syncthreads();
    if (it < 4) {                       // prefetch next chunk, hides under compute
      const unsigned short* p = ftb + (size_t)(colg * 5 + it + 1) * 48 * 128;
#pragma unroll
      for (int i = 0; i < 3; i++) r[i] = *(const uint4*)(p + rowoff[i]);
    }
    f32x4 acc[4][3];
#pragma unroll
    for (int tile = 0; tile < 4; tile++)
#pragma unroll
      for (int sub = 0; sub < 3; sub++) acc[tile][sub] = (f32x4){0.f, 0.f, 0.f, 0.f};
#pragma unroll
    for (int kk = 0; kk < 4; kk++) {
      bf16x8 bv[3];
#pragma unroll
      for (int sub = 0; sub < 3; sub++)
        bv[sub] = *(const bf16x8*)&bufp[(kk * 3 + sub) * 512 + lane * 8];
#pragma unroll
      for (int tile = 0; tile < 4; tile++)
#pragma unroll
        for (int sub = 0; sub < 3; sub++)
          acc[tile][sub] = __builtin_amdgcn_mfma_f32_16x16x32_bf16(
              a[tile][kk], bv[sub], acc[tile][sub], 0, 0, 0);
    }
#pragma unroll
    for (int tile = 0; tile < 4; tile++)
#pragma unroll
      for (int sub = 0; sub < 3; sub++)
#pragma unroll
        for (int i = 0; i < 4; i++)
          rs[tile][i] += exp2f(acc[tile][sub][i]);
    // single barrier per iter is sufficient with the double buffer (verified r4/r5)
  }

  // reduce col-partials over lanes 0-15 of each group
#pragma unroll
  for (int tile = 0; tile < 4; tile++)
#pragma unroll
    for (int i = 0; i < 4; i++) {
      float v = rs[tile][i];
      v += __shfl_xor(v, 1); v += __shfl_xor(v, 2);
      v += __shfl_xor(v, 4); v += __shfl_xor(v, 8);
      rs[tile][i] = v;
    }
  if (lr == 0) {
    float* out = slab + (size_t)colg * NQ + b * HW;
#pragma unroll
    for (int tile = 0; tile < 4; tile++)
#pragma unroll
      for (int i = 0; i < 4; i++) {
        const int rr = base + tile * 16 + lkq * 4 + i;
        if (rr < HW) out[rr] = rs[tile][i];
      }
  }
}

// ---------------- final: mean over q of (log(sum_colg slab) - dot*ln2)
// (features carry sqrt(INV_T*log2e), so dot*ln2 == raw_dot*INV_T)
__global__ __launch_bounds__(256) void final_kernel(
    const float* __restrict__ slab, const unsigned short* __restrict__ fo,
    const unsigned short* __restrict__ ft, float* __restrict__ out) {
  const int q = blockIdx.x * 256 + threadIdx.x;
  float val = 0.f;
  if (q < NQ) {
    float se = 0.f;
#pragma unroll
    for (int s = 0; s < 15; s++) se += slab[(size_t)s * NQ + q];
    const unsigned short* a = fo + (size_t)q * 128;
    const unsigned short* c = ft + (size_t)q * 128;
    float dot = 0.f;
#pragma unroll
    for (int k = 0; k < 128; k += 8) {
      bf16x8 ua = *(const bf16x8*)(a + k);
      bf16x8 ub = *(const bf16x8*)(c + k);
#pragma unroll
      for (int e = 0; e < 8; e++)
        dot = fmaf(bf2f((unsigned short)ua[e]), bf2f((unsigned short)ub[e]), dot);
    }
    val = logf(se) - dot * LN2F;
  }
#pragma unroll
  for (int m = 1; m < 64; m <<= 1) val += __shfl_xor(val, m);
  __shared__ float red[4];
  const int wid = threadIdx.x >> 6;
  if ((threadIdx.x & 63) == 0) red[wid] = val;
  __syncthreads();
  if (threadIdx.x == 0)
    atomicAdd(out, (red[0] + red[1] + red[2] + red[3]) * (1.f / (float)NQ));
}

extern "C" void kernel_launch(void* const* d_in, const int* in_sizes, int n_in,
                              void* d_out, int out_size, void* d_ws, size_t ws_size,
                              hipStream_t stream) {
  (void)in_sizes; (void)n_in; (void)out_size; (void)ws_size;
  const float* x_orig = (const float*)d_in[0];
  const float* x_trans = (const float*)d_in[1];
  const float* conv_w = (const float*)d_in[2];
  const float* conv_b = (const float*)d_in[3];
  const float* gamma = (const float*)d_in[4];
  const float* beta = (const float*)d_in[5];
  const float* lin_w = (const float*)d_in[6];
  const float* lin_b = (const float*)d_in[7];
  float* out = (float*)d_out;

  char* ws = (char*)d_ws;
  unsigned short* yt = (unsigned short*)(ws + 0);            // 2 x 7,372,800 B (phase A)
  float* slab = (float*)(ws + 0);                            // 15 x 28800 x 4 = 1,728,000 B
                                                             //   (aliases yt: dead by infonce)
  unsigned short* cw16 = (unsigned short*)(ws + 14745600);   //     65,536 B
  unsigned short* lw16 = (unsigned short*)(ws + 14811136);   //     32,768 B
  float* stats = (float*)(ws + 14843904);                    //     32,768 B (2 x 16 x 256)
  float* sc = (float*)(ws + 14876672);                       //      2,048 B
  unsigned short* feat_o = (unsigned short*)(ws + 14878720); //  7,372,800 B
  unsigned short* feat_t = (unsigned short*)(ws + 22251520); //  7,372,800 B
  // end: 29,624,320 B

  hipMemsetAsync(stats, 0, 32768, stream);
  hipMemsetAsync(d_out, 0, sizeof(float), stream);

  prep_kernel<<<128, 256, 0, stream>>>(conv_w, lin_w, cw16, lw16);

  conv1_mfma_kernel<<<dim3(450, 1, 2), 256, 0, stream>>>(x_orig, x_trans, cw16, yt, stats);
  scale_kernel<<<2, 128, 0, stream>>>(stats, conv_b, gamma, beta, sc);
  conv2_mfma_kernel<<<dim3(450, 1, 2), 256, 0, stream>>>(yt, lw16, sc, lin_b, feat_o, feat_t);

  infonce_kernel<<<1800, 256, 0, stream>>>(feat_o, feat_t, slab);
  final_kernel<<<113, 256, 0, stream>>>(slab, feat_o, feat_t, out);
}